// Round 12
// baseline (100.220 us; speedup 1.0000x reference)
//
#include <hip/hip_runtime.h>
#include <hip/hip_bf16.h>

#define NBLK 8
#define DIN 512
#define DOUT 512
#define NFEAT 4096      // NBLK * DIN
#define BATCH 8192
#define NT 16           // DIN / 32 K-steps
#define BM 128
#define BN 128

typedef __attribute__((ext_vector_type(8))) short short8;
typedef __attribute__((ext_vector_type(4))) float f32x4;

static __device__ __forceinline__ short f2bf16(float f) {
  __bf16 h = (__bf16)f;               // RNE; compiler packs into v_cvt_pk_bf16_f32
  return __builtin_bit_cast(short, h);
}

static __device__ __forceinline__ short8 cvt8(f32x4 lo, f32x4 hi) {
  short8 o;
  o[0] = f2bf16(lo[0]); o[1] = f2bf16(lo[1]); o[2] = f2bf16(lo[2]); o[3] = f2bf16(lo[3]);
  o[4] = f2bf16(hi[0]); o[5] = f2bf16(hi[1]); o[6] = f2bf16(hi[2]); o[7] = f2bf16(hi[3]);
  return o;
}

static __device__ __forceinline__ void gload_lds16(const void* g, void* l) {
  __builtin_amdgcn_global_load_lds(
      (const __attribute__((address_space(1))) void*)g,
      (__attribute__((address_space(3))) void*)l, 16, 0, 0);
}

// R12: SINGLE kernel — no wprep pre-pass (it cost ~12 us of every timed
// graph since R3). B is staged as fp32 straight from W; the fp32->bf16
// conversion rides the same cvt8-at-fragment-read path A always used
// (VALU is ~10% busy — free). W's [col][k] layout is the exact mirror of
// x's [row][k], so B staging/reading reuses A's proven swizzle verbatim.
//
// 128x128 tile, 256 threads, 4 waves (2x2), wave tile 64x64 (acc=64).
// A fp32 2-buf (2x16KB) + B fp32 2-buf (2x16KB) = 64 KB -> 2 blocks/CU;
// the co-resident block covers the distance-1 vmcnt(0) drain (R11-proven).
// Race-free 2-buf: every ds_read of buf (t+1)&1 was consumed (lgkmcnt
// before MFMA) before this wave hit barrier(t); DMA writes follow the
// barrier -> no overlap.
__global__ __launch_bounds__(256, 2) void blocklinear_kernel(
    const float* __restrict__ x, const float* __restrict__ W,
    const float* __restrict__ bias, float* __restrict__ y)
{
  // XCD swizzle (bijective: 2048 % 8 == 0): one nb per XCD, nt innermost
  // (4 nt-siblings share an x M-panel on one XCD's L2/L3 path).
  const int b       = blockIdx.x;
  const int logical = (b & 7) * 256 + (b >> 3);
  const int nb  = logical >> 8;
  const int rem = logical & 255;
  const int mt  = rem >> 2;    // 0..63
  const int nt  = rem & 3;     // 0..3

  const int tid  = threadIdx.x;
  const int lane = tid & 63;
  const int w    = tid >> 6;   // wave 0..3
  const int wr   = w >> 1;     // M-row 0..1 (rows wr*64..+64)
  const int wc   = w & 1;      // N-col 0..1 (cols wc*64..+64)
  const int l15  = lane & 15;
  const int k16  = lane >> 4;

  __shared__ __align__(16) float Abuf[2][BM * 32];   // 2 x 16 KB
  __shared__ __align__(16) float Bbuf[2][BN * 32];   // 2 x 16 KB  (64 KB)

  // --- staging (A rows of x, B cols of W — identical pattern):
  // 16 x 1KB DMAs per tile; wave w does 4 (i=0..3), rows/cols w*32+i*8+(l>>3),
  // dest chunk l&7 (linear); source chunk pre-XOR'd (l&7)^(l>>3):
  // stored slot s of row r holds data chunk s^(r&7).
  const int l8 = lane >> 3;
  const int c  = lane & 7;
  const float* asrc[4];
  const float* bsrc[4];
#pragma unroll
  for (int i = 0; i < 4; ++i) {
    const int rl = w * 32 + i * 8 + l8;            // local row / col index
    const int gr = mt * BM + rl;                   // global x row
    const int gc = nt * BN + rl;                   // global W col (out-feature)
    asrc[i] = x + (size_t)gr * NFEAT + nb * DIN + ((c ^ l8) << 2);
    bsrc[i] = W + (size_t)nb * DOUT * DIN + (size_t)gc * DIN + ((c ^ l8) << 2);
  }

#define STAGE(buf, t)                                                       \
  {                                                                         \
    _Pragma("unroll")                                                       \
    for (int i = 0; i < 4; ++i)                                             \
      gload_lds16(asrc[i] + (t) * 32, &Abuf[buf][(w * 32 + i * 8) * 32]);   \
    _Pragma("unroll")                                                       \
    for (int i = 0; i < 4; ++i)                                             \
      gload_lds16(bsrc[i] + (t) * 32, &Bbuf[buf][(w * 32 + i * 8) * 32]);   \
  }

  // --- fragment read offsets (floats): row = base + m*16 + l15
  // (row&7 == l15&7); addr = row*32 + slot*4, slot = (2k16 / 2k16+1)^(l15&7).
  const int ra_base = (wr * 64 + l15) * 32;
  const int ra_lo   = ra_base + (((2 * k16)     ^ (l15 & 7)) << 2);
  const int ra_hi   = ra_base + (((2 * k16 + 1) ^ (l15 & 7)) << 2);
  const int rb_base = (wc * 64 + l15) * 32;
  const int rb_lo   = rb_base + (((2 * k16)     ^ (l15 & 7)) << 2);
  const int rb_hi   = rb_base + (((2 * k16 + 1) ^ (l15 & 7)) << 2);

  f32x4 acc[4][4];
#pragma unroll
  for (int m = 0; m < 4; ++m)
#pragma unroll
    for (int n = 0; n < 4; ++n)
      acc[m][n] = (f32x4){0.f, 0.f, 0.f, 0.f};

#define COMPUTE(buf)                                                        \
  {                                                                         \
    const float* la = &Abuf[buf][0];                                        \
    const float* lb = &Bbuf[buf][0];                                        \
    short8 af[4], bf[4];                                                    \
    _Pragma("unroll")                                                       \
    for (int m = 0; m < 4; ++m) {                                           \
      f32x4 lo = *(const f32x4*)(la + m * 512 + ra_lo);                     \
      f32x4 hi = *(const f32x4*)(la + m * 512 + ra_hi);                     \
      af[m] = cvt8(lo, hi);                                                 \
    }                                                                       \
    _Pragma("unroll")                                                       \
    for (int n = 0; n < 4; ++n) {                                           \
      f32x4 lo = *(const f32x4*)(lb + n * 512 + rb_lo);                     \
      f32x4 hi = *(const f32x4*)(lb + n * 512 + rb_hi);                     \
      bf[n] = cvt8(lo, hi);                                                 \
    }                                                                       \
    __builtin_amdgcn_s_setprio(1);                                          \
    _Pragma("unroll")                                                       \
    for (int m = 0; m < 4; ++m)                                             \
      _Pragma("unroll")                                                     \
      for (int n = 0; n < 4; ++n)                                           \
        acc[m][n] = __builtin_amdgcn_mfma_f32_16x16x32_bf16(af[m], bf[n], acc[m][n], 0, 0, 0); \
    __builtin_amdgcn_s_setprio(0);                                          \
  }

  // Step t: drain stage(t) (issued last step; drain covered by the
  // co-resident block); barrier; stage(t+1) into the buffer whose reads all
  // retired before the barrier; compute(t).
#define STEP(t)                                                             \
  {                                                                         \
    __builtin_amdgcn_sched_barrier(0);                                      \
    asm volatile("s_waitcnt vmcnt(0)" ::: "memory");                        \
    __builtin_amdgcn_s_barrier();                                           \
    __builtin_amdgcn_sched_barrier(0);                                      \
    if ((t) + 1 < NT) STAGE(((t) + 1) & 1, (t) + 1);                        \
    COMPUTE((t) & 1);                                                       \
  }

  STAGE(0, 0);

  STEP(0)  STEP(1)  STEP(2)  STEP(3)
  STEP(4)  STEP(5)  STEP(6)  STEP(7)
  STEP(8)  STEP(9)  STEP(10) STEP(11)
  STEP(12) STEP(13) STEP(14) STEP(15)

  // epilogue: C/D layout col = lane&15, row = (lane>>4)*4 + j  [m89-verified]
  const int col0 = nt * BN + wc * 64;
  const int row0 = mt * BM + wr * 64;
  const float* bptr = bias + nb * DOUT + col0;
#pragma unroll
  for (int n = 0; n < 4; ++n) {
    const float bv = bptr[n * 16 + l15];
    const size_t col = (size_t)nb * DOUT + col0 + n * 16 + l15;
#pragma unroll
    for (int m = 0; m < 4; ++m) {
      const int row = row0 + m * 16 + k16 * 4;
      float* yp = y + (size_t)row * NFEAT + col;
#pragma unroll
      for (int j = 0; j < 4; ++j)
        yp[(size_t)j * NFEAT] = acc[m][n][j] + bv;
    }
  }
}

extern "C" void kernel_launch(void* const* d_in, const int* in_sizes, int n_in,
                              void* d_out, int out_size, void* d_ws, size_t ws_size,
                              hipStream_t stream) {
  const float* x  = (const float*)d_in[0];
  const float* W  = (const float*)d_in[1];
  const float* bi = (const float*)d_in[2];
  float* y = (float*)d_out;
  const int grid = NBLK * (BATCH / BM) * (DOUT / BN);   // 2048
  blocklinear_kernel<<<grid, 256, 0, stream>>>(x, W, bi, y);
}